// Round 8
// baseline (299.031 us; speedup 1.0000x reference)
//
#include <hip/hip_runtime.h>
#include <math.h>

#define SLEN 2048
#define BATCH 8
#define DMODEL 256
#define HEADS 8
#define DPROJ 128
#define DFF 1024
#define DH 16
#define MROWS (SLEN*BATCH)   // 16384
#define NROWS (SLEN*BATCH*8) // 131072 q-rows across bh

typedef unsigned short u16;
typedef unsigned int u32;
typedef __attribute__((ext_vector_type(8))) short short8;
typedef __attribute__((ext_vector_type(4))) float f32x4;
typedef __attribute__((ext_vector_type(16))) float f32x16;
typedef __attribute__((ext_vector_type(4))) unsigned short u16x4;

__device__ __forceinline__ u16 f2bf(float x) {
    union { float f; u32 u; } v; v.f = x;
    u32 r = v.u + 0x7FFFu + ((v.u >> 16) & 1u);
    return (u16)(r >> 16);
}
__device__ __forceinline__ float bf2f(u16 h) {
    union { u32 u; float f; } v; v.u = ((u32)h) << 16;
    return v.f;
}
__device__ __forceinline__ float fexp2(float x) { return __builtin_amdgcn_exp2f(x); }
// pack bf16(lo),bf16(hi) (truncating) into one dword via v_perm_b32; the
// truncation bias cancels in O/L since L is computed from the same truncated P
__device__ __forceinline__ u32 pack_bf(float lo, float hi) {
    union { float f; u32 u; } a, b; a.f = lo; b.f = hi;
    return __builtin_amdgcn_perm(b.u, a.u, 0x07060302u);
}
// async global->LDS 16B: per-lane global addr, wave-uniform LDS base
__device__ __forceinline__ void gld16(const u16* g, u16* l) {
    __builtin_amdgcn_global_load_lds(
        (const __attribute__((address_space(1))) void*)g,
        (__attribute__((address_space(3))) void*)l, 16, 0, 0);
}

// ---------------------------------------------------------------------------
// prep: src fp32->bf16 (blocks 0..4095) + weight transpose+convert (rest)
// ---------------------------------------------------------------------------
__global__ void prep_kernel(const float* __restrict__ src, u16* __restrict__ srcb,
                            const float* __restrict__ Wq, const float* __restrict__ Wk,
                            const float* __restrict__ Wv, const float* __restrict__ Wo,
                            const float* __restrict__ W1, const float* __restrict__ W2,
                            u16* __restrict__ WqT, u16* __restrict__ WkT,
                            u16* __restrict__ WvT, u16* __restrict__ WoT,
                            u16* __restrict__ W1T, u16* __restrict__ W2T) {
    if (blockIdx.x < 4096) {
        int idx = (blockIdx.x * 256 + threadIdx.x) * 4;
        float4 v = *(const float4*)(src + idx);
        u16x4 o;
        o.x = f2bf(v.x); o.y = f2bf(v.y); o.z = f2bf(v.z); o.w = f2bf(v.w);
        *(u16x4*)(srcb + idx) = o;
        return;
    }
    int i = (blockIdx.x - 4096) * 256 + threadIdx.x;
    if (i < 32768) {                       // WqT [128][256]
        int n = i >> 8, k = i & 255;
        WqT[i] = f2bf(Wq[k * 128 + n]);
    } else if (i < 65536) {
        int j = i - 32768; int n = j >> 8, k = j & 255;
        WkT[j] = f2bf(Wk[k * 128 + n]);
    } else if (i < 98304) {
        int j = i - 65536; int n = j >> 8, k = j & 255;
        WvT[j] = f2bf(Wv[k * 128 + n]);
    } else if (i < 131072) {               // WoT [256][128]
        int j = i - 98304; int n = j >> 7, k = j & 127;
        WoT[j] = f2bf(Wo[k * 256 + n]);
    } else if (i < 393216) {               // W1T [1024][256]
        int j = i - 131072; int n = j >> 8, k = j & 255;
        W1T[j] = f2bf(W1[k * 1024 + n]);
    } else if (i < 655360) {               // W2T [256][1024]
        int j = i - 393216; int n = j >> 10, k = j & 1023;
        W2T[j] = f2bf(W2[k * 256 + n]);
    }
}

// ---------------------------------------------------------------------------
// bf16 MFMA GEMM with async global->LDS staging + XOR chunk swizzle.
// ---------------------------------------------------------------------------
template<int BN, bool RELU, bool HAS_BIAS, bool OUT_BF16>
__global__ void mfma_gemm(const u16* __restrict__ A, const u16* __restrict__ BT,
                          const float* __restrict__ bias, void* __restrict__ Cout,
                          int M, int N, int K) {
    constexpr int NJ = BN / 32;
    __shared__ __align__(16) u16 As[128 * 32];
    __shared__ __align__(16) u16 Bs[BN * 32];
    const int tid = threadIdx.x;
    const int row0 = blockIdx.x * 128;
    const int col0 = blockIdx.y * BN;
    const int w = tid >> 6, l = tid & 63;
    const int wr = (w & 1) * 64, wc = (w >> 1) * (BN / 2);
    const int lcol = l & 15, lrow = (l >> 4) * 4, g = l >> 4;
    const int sl = l >> 2;
    const int swc = ((l & 3) ^ (sl & 3)) * 8;
    const int fsw = (g ^ (lcol & 3)) * 8;

    const u16* Ag0 = A + (size_t)(row0 + 16 * w + sl) * K + swc;
    const u16* Ag1 = Ag0 + (size_t)64 * K;
    const u16* Bg0 = BT + (size_t)(col0 + 16 * w + sl) * K + swc;
    const u16* Bg1 = Bg0 + (size_t)64 * K;
    u16* lA0 = As + (16 * w) * 32;
    u16* lA1 = As + (16 * w + 64) * 32;
    u16* lB0 = Bs + (16 * w) * 32;
    u16* lB1 = Bs + (16 * w + 64) * 32;

    f32x4 acc[4][NJ] = {};
    for (int k0 = 0; k0 < K; k0 += 32) {
        gld16(Ag0 + k0, lA0);
        gld16(Ag1 + k0, lA1);
        gld16(Bg0 + k0, lB0);
        if (BN == 128) gld16(Bg1 + k0, lB1);
        __syncthreads();
        short8 af[4], bf[NJ];
        #pragma unroll
        for (int i = 0; i < 4; ++i)
            af[i] = *(const short8*)(As + (wr + i * 16 + lcol) * 32 + fsw);
        #pragma unroll
        for (int j = 0; j < NJ; ++j)
            bf[j] = *(const short8*)(Bs + (wc + j * 16 + lcol) * 32 + fsw);
        #pragma unroll
        for (int i = 0; i < 4; ++i)
            #pragma unroll
            for (int j = 0; j < NJ; ++j)
                acc[i][j] = __builtin_amdgcn_mfma_f32_16x16x32_bf16(
                    af[i], bf[j], acc[i][j], 0, 0, 0);
        __syncthreads();
    }
    float bv[NJ];
    #pragma unroll
    for (int j = 0; j < NJ; ++j)
        bv[j] = HAS_BIAS ? bias[col0 + wc + j * 16 + lcol] : 0.f;
    #pragma unroll
    for (int i = 0; i < 4; ++i) {
        #pragma unroll
        for (int r = 0; r < 4; ++r) {
            size_t grow = row0 + wr + i * 16 + lrow + r;
            #pragma unroll
            for (int j = 0; j < NJ; ++j) {
                int gcol = col0 + wc + j * 16 + lcol;
                float c = acc[i][j][r] + bv[j];
                if (RELU) c = fmaxf(c, 0.f);
                if (OUT_BF16) ((u16*)Cout)[grow * N + gcol] = f2bf(c);
                else          ((float*)Cout)[grow * N + gcol] = c;
            }
        }
    }
}

// ---------------------------------------------------------------------------
// QKV MFMA GEMM -> TIGHT bf16 head-layout [bh][s][16] for q, k, v.
// q pre-scaled by 0.25*log2e.
// ---------------------------------------------------------------------------
__global__ void qkv_mfma(const u16* __restrict__ A,
                         const u16* __restrict__ WqT, const u16* __restrict__ WkT,
                         const u16* __restrict__ WvT,
                         const float* __restrict__ bq, const float* __restrict__ bk,
                         const float* __restrict__ bv,
                         u16* __restrict__ qhp, u16* __restrict__ khp,
                         u16* __restrict__ vhb) {
    const int which = blockIdx.z;
    const u16* BT   = which == 0 ? WqT : (which == 1 ? WkT : WvT);
    const float* bs = which == 0 ? bq : (which == 1 ? bk : bv);
    u16* outp       = which == 0 ? qhp : (which == 1 ? khp : vhb);
    const float scale = which == 0 ? 0.25f * 1.44269504f : 1.0f;
    __shared__ __align__(16) u16 As[128 * 32];
    __shared__ __align__(16) u16 Bs[128 * 32];
    const int tid = threadIdx.x;
    const int row0 = blockIdx.x * 128;
    const int w = tid >> 6, l = tid & 63;
    const int wr = (w & 1) * 64, wc = (w >> 1) * 64;
    const int lcol = l & 15, lrow = (l >> 4) * 4, g = l >> 4;
    const int sl = l >> 2;
    const int swc = ((l & 3) ^ (sl & 3)) * 8;
    const int fsw = (g ^ (lcol & 3)) * 8;

    const u16* Ag0 = A + (size_t)(row0 + 16 * w + sl) * DMODEL + swc;
    const u16* Ag1 = Ag0 + (size_t)64 * DMODEL;
    const u16* Bg0 = BT + (size_t)(16 * w + sl) * DMODEL + swc;
    const u16* Bg1 = Bg0 + (size_t)64 * DMODEL;
    u16* lA0 = As + (16 * w) * 32;
    u16* lA1 = As + (16 * w + 64) * 32;
    u16* lB0 = Bs + (16 * w) * 32;
    u16* lB1 = Bs + (16 * w + 64) * 32;

    f32x4 acc[4][4] = {};
    for (int k0 = 0; k0 < DMODEL; k0 += 32) {
        gld16(Ag0 + k0, lA0);
        gld16(Ag1 + k0, lA1);
        gld16(Bg0 + k0, lB0);
        gld16(Bg1 + k0, lB1);
        __syncthreads();
        short8 af[4], bf[4];
        #pragma unroll
        for (int i = 0; i < 4; ++i)
            af[i] = *(const short8*)(As + (wr + i * 16 + lcol) * 32 + fsw);
        #pragma unroll
        for (int j = 0; j < 4; ++j)
            bf[j] = *(const short8*)(Bs + (wc + j * 16 + lcol) * 32 + fsw);
        #pragma unroll
        for (int i = 0; i < 4; ++i)
            #pragma unroll
            for (int j = 0; j < 4; ++j)
                acc[i][j] = __builtin_amdgcn_mfma_f32_16x16x32_bf16(
                    af[i], bf[j], acc[i][j], 0, 0, 0);
        __syncthreads();
    }
    #pragma unroll
    for (int i = 0; i < 4; ++i) {
        #pragma unroll
        for (int r = 0; r < 4; ++r) {
            int grow = row0 + wr + i * 16 + lrow + r;
            int b = grow & 7, s = grow >> 3;
            #pragma unroll
            for (int j = 0; j < 4; ++j) {
                int gcol = wc + j * 16 + lcol;
                int h = gcol >> 4, d = gcol & 15;
                float c = acc[i][j][r] + bs[gcol];
                outp[((size_t)(b * 8 + h) * SLEN + s) * 16 + d] = f2bf(c * scale);
            }
        }
    }
}

// ---------------------------------------------------------------------------
// V transpose+augment: vhb [bh][s][16] -> va [bh][32][2048]
// rows 0..15 = V^T, row 16 = 1.0 (bf16), rows 17..31 garbage (ignored).
// ---------------------------------------------------------------------------
__global__ void transpose_v(const u16* __restrict__ vhb, u16* __restrict__ va) {
    __shared__ u16 T[128 * 24];
    const int bh = blockIdx.y;
    const int c0 = blockIdx.x * 128;
    const int t = threadIdx.x;
    {
        int key = t >> 1, half = t & 1;
        *(uint4*)(T + key * 24 + half * 8) =
            *(const uint4*)(vhb + ((size_t)bh * SLEN + c0 + key) * 16 + half * 8);
    }
    __syncthreads();
    int d = t >> 4, k8 = (t & 15) * 8;
    u16x4 o0, o1;
    o0.x = T[(k8 + 0) * 24 + d]; o0.y = T[(k8 + 1) * 24 + d];
    o0.z = T[(k8 + 2) * 24 + d]; o0.w = T[(k8 + 3) * 24 + d];
    o1.x = T[(k8 + 4) * 24 + d]; o1.y = T[(k8 + 5) * 24 + d];
    o1.z = T[(k8 + 6) * 24 + d]; o1.w = T[(k8 + 7) * 24 + d];
    u16* dst = va + ((size_t)bh * 32 + d) * SLEN + c0 + k8;
    *(u16x4*)dst = o0;
    *(u16x4*)(dst + 4) = o1;
    if (t < 16) {   // ones row (row 16)
        u16x4 ones = { (u16)0x3F80, (u16)0x3F80, (u16)0x3F80, (u16)0x3F80 };
        u16* od = va + ((size_t)bh * 32 + 16) * SLEN + c0 + t * 8;
        *(u16x4*)od = ones;
        *(u16x4*)(od + 4) = ones;
    }
}

// ---------------------------------------------------------------------------
// MFMA flash attention v6 — split-K=2 partial-sum flash (no-max softmax makes
// O,L pure sums), 2-wave blocks (4096 blocks -> 16 blocks/CU, 32 waves/CU),
// single-buffered per-wave P (DS ops are in-order per wave -> WAR safe).
// P stride 68 u16 = 34 dwords === 2 (mod 32): all stores/reads are b64 with
// exactly 4 dwords/bank/instr (wave64 b64 minimum -> zero conflicts).
// Per 64-key tile: 2 QK MFMAs (32x32x16, K=dh=16), exp2+v_perm pack,
// 8 b64 P-stores, 8 b64 P-reads, 4 PV MFMAs vs ones-augmented V (L free in
// col 16). Epilogue stores raw fp32 partials [slice][row][20]; combine
// kernel sums slices, normalizes, emits ctx bf16.
// ---------------------------------------------------------------------------
__global__ __launch_bounds__(128, 8)
void attn_mfma(const u16* __restrict__ qg, const u16* __restrict__ kg,
               const u16* __restrict__ va, float* __restrict__ part) {
    __shared__ __align__(16) u16 Ps[2 * 32 * 68];   // 8704 B (4352/wave)
    const int bh = blockIdx.y;
    const int sl = blockIdx.z;
    const int tid = threadIdx.x;
    const int w = tid >> 6, l = tid & 63;
    const int n = l & 31, h5 = l >> 5;
    u16* Pw = Ps + w * (32 * 68);

    const int qbase = blockIdx.x * 64 + w * 32;
    const short8 qf = *(const short8*)(
        qg + ((size_t)bh * SLEN + qbase + n) * 16 + h5 * 8);
    const u16* kb = kg + (size_t)bh * SLEN * 16;
    const u16* vb = va + ((size_t)bh * 32 + n) * SLEN + h5 * 8;
    const int k00 = sl * (SLEN / 2);

    f32x16 oacc = {};
    short8 kf0 = *(const short8*)(kb + (size_t)(k00 + n) * 16 + h5 * 8);
    short8 kf1 = *(const short8*)(kb + (size_t)(k00 + 32 + n) * 16 + h5 * 8);

    for (int kt = 0; kt < 16; ++kt) {
        const int k0 = k00 + kt * 64;
        short8 vf[4];
        #pragma unroll
        for (int st = 0; st < 4; ++st)
            vf[st] = *(const short8*)(vb + k0 + st * 16);
        // S^T = K·Q^T (D[m=key][n=qrow])
        f32x16 z = {};
        f32x16 s0 = __builtin_amdgcn_mfma_f32_32x32x16_bf16(kf0, qf, z, 0, 0, 0);
        f32x16 s1 = __builtin_amdgcn_mfma_f32_32x32x16_bf16(kf1, qf, z, 0, 0, 0);
        // prefetch next tile's K fragments
        const int kn = k00 + ((kt + 1) & 15) * 64;
        kf0 = *(const short8*)(kb + (size_t)(kn + n) * 16 + h5 * 8);
        kf1 = *(const short8*)(kb + (size_t)(kn + 32 + n) * 16 + h5 * 8);
        // P = exp2(S): reg quad r4 covers keys 8r4 + 4h5 + {0..3}
        #pragma unroll
        for (int r4 = 0; r4 < 4; ++r4) {
            uint2 d;
            d.x = pack_bf(fexp2(s0[r4 * 4 + 0]), fexp2(s0[r4 * 4 + 1]));
            d.y = pack_bf(fexp2(s0[r4 * 4 + 2]), fexp2(s0[r4 * 4 + 3]));
            *(uint2*)(Pw + n * 68 + 8 * r4 + 4 * h5) = d;
        }
        #pragma unroll
        for (int r4 = 0; r4 < 4; ++r4) {
            uint2 d;
            d.x = pack_bf(fexp2(s1[r4 * 4 + 0]), fexp2(s1[r4 * 4 + 1]));
            d.y = pack_bf(fexp2(s1[r4 * 4 + 2]), fexp2(s1[r4 * 4 + 3]));
            *(uint2*)(Pw + n * 68 + 32 + 8 * r4 + 4 * h5) = d;
        }
        // O(+L) += P @ Vaug : A[m=q][k=key], B[k=key][n=dh|L]
        #pragma unroll
        for (int st = 0; st < 4; ++st) {
            const u16* rp = Pw + n * 68 + st * 16 + h5 * 8;
            union { uint2 q2[2]; short8 v; } ap;
            ap.q2[0] = *(const uint2*)rp;
            ap.q2[1] = *(const uint2*)(rp + 4);
            oacc = __builtin_amdgcn_mfma_f32_32x32x16_bf16(ap.v, vf[st], oacc, 0, 0, 0);
        }
    }
    // partial epilogue: raw fp32 O (cols 0..15) and L (col 16), row stride 20
    float* pr = part + ((size_t)sl * NROWS + (size_t)bh * SLEN + qbase) * 20;
    if (n <= 16) {
        #pragma unroll
        for (int r = 0; r < 16; ++r) {
            int qq = (r & 3) + 8 * (r >> 2) + 4 * h5;
            pr[(size_t)qq * 20 + n] = oacc[r];
        }
    }
}

// ---------------------------------------------------------------------------
// combine: ctx = (O0 + O1) / (L0 + L1), bf16 row-major (S*B, 128)
// ---------------------------------------------------------------------------
__global__ void attn_combine(const float* __restrict__ part, u16* __restrict__ ctx) {
    int idx = blockIdx.x * 256 + threadIdx.x;   // 262144 = 131072 rows x 2
    int row = idx >> 1, half = idx & 1;
    const float* b0 = part + (size_t)row * 20;
    const float* b1 = b0 + (size_t)NROWS * 20;
    f32x4 a0 = *(const f32x4*)(b0 + half * 8);
    f32x4 a1 = *(const f32x4*)(b0 + half * 8 + 4);
    f32x4 c0 = *(const f32x4*)(b1 + half * 8);
    f32x4 c1 = *(const f32x4*)(b1 + half * 8 + 4);
    float rcp = 1.0f / (b0[16] + b1[16]);
    u16x4 p0, p1;
    p0.x = f2bf((a0[0] + c0[0]) * rcp); p0.y = f2bf((a0[1] + c0[1]) * rcp);
    p0.z = f2bf((a0[2] + c0[2]) * rcp); p0.w = f2bf((a0[3] + c0[3]) * rcp);
    p1.x = f2bf((a1[0] + c1[0]) * rcp); p1.y = f2bf((a1[1] + c1[1]) * rcp);
    p1.z = f2bf((a1[2] + c1[2]) * rcp); p1.w = f2bf((a1[3] + c1[3]) * rcp);
    int bh = row >> 11, q = row & 2047, b = bh >> 3, h = bh & 7;
    u16* dst = ctx + ((size_t)q * BATCH + b) * DPROJ + h * DH + half * 8;
    *(u16x4*)dst = p0;
    *(u16x4*)(dst + 4) = p1;
}

// ---------------------------------------------------------------------------
// LN, wave-per-row (64 lanes x 4 elems), no barriers.
// ---------------------------------------------------------------------------
__global__ void ln1_kernel(const float* __restrict__ src, const u16* __restrict__ y,
                           const float* __restrict__ g, const float* __restrict__ bb,
                           u16* __restrict__ xb) {
    const int w = threadIdx.x >> 6, l = threadIdx.x & 63;
    const int row = blockIdx.x * 4 + w;
    const int c = l * 4;
    size_t base = (size_t)row * DMODEL;
    float4 s4 = *(const float4*)(src + base + c);
    u16x4 y4 = *(const u16x4*)(y + base + c);
    float v[4] = { s4.x + bf2f(y4.x), s4.y + bf2f(y4.y),
                   s4.z + bf2f(y4.z), s4.w + bf2f(y4.w) };
    float sum = v[0] + v[1] + v[2] + v[3];
    float ss  = v[0]*v[0] + v[1]*v[1] + v[2]*v[2] + v[3]*v[3];
    #pragma unroll
    for (int off = 1; off < 64; off <<= 1) {
        sum += __shfl_xor(sum, off);
        ss  += __shfl_xor(ss, off);
    }
    float mu = sum * (1.0f / 256.0f);
    float var = ss * (1.0f / 256.0f) - mu * mu;
    float rs = rsqrtf(var + 1e-5f);
    float4 g4 = *(const float4*)(g + c);
    float4 b4 = *(const float4*)(bb + c);
    u16x4 o;
    o.x = f2bf((v[0] - mu) * rs * g4.x + b4.x);
    o.y = f2bf((v[1] - mu) * rs * g4.y + b4.y);
    o.z = f2bf((v[2] - mu) * rs * g4.z + b4.z);
    o.w = f2bf((v[3] - mu) * rs * g4.w + b4.w);
    *(u16x4*)(xb + base + c) = o;
}

__global__ void ln2_kernel(const u16* __restrict__ x, const u16* __restrict__ f,
                           const float* __restrict__ g, const float* __restrict__ bb,
                           float* __restrict__ out) {
    const int w = threadIdx.x >> 6, l = threadIdx.x & 63;
    const int row = blockIdx.x * 4 + w;
    const int c = l * 4;
    size_t base = (size_t)row * DMODEL;
    u16x4 x4 = *(const u16x4*)(x + base + c);
    u16x4 f4 = *(const u16x4*)(f + base + c);
    float v[4] = { bf2f(x4.x) + bf2f(f4.x), bf2f(x4.y) + bf2f(f4.y),
                   bf2f(x4.z) + bf2f(f4.z), bf2f(x4.w) + bf2f(f4.w) };
    float sum = v[0] + v[1] + v[2] + v[3];
    float ss  = v[0]*v[0] + v[1]*v[1] + v[2]*v[2] + v[3]*v[3];
    #pragma unroll
    for (int off = 1; off < 64; off <<= 1) {
        sum += __shfl_xor(sum, off);
        ss  += __shfl_xor(ss, off);
    }
    float mu = sum * (1.0f / 256.0f);
    float var = ss * (1.0f / 256.0f) - mu * mu;
    float rs = rsqrtf(var + 1e-5f);
    float4 g4 = *(const float4*)(g + c);
    float4 b4 = *(const float4*)(bb + c);
    float4 o;
    o.x = (v[0] - mu) * rs * g4.x + b4.x;
    o.y = (v[1] - mu) * rs * g4.y + b4.y;
    o.z = (v[2] - mu) * rs * g4.z + b4.z;
    o.w = (v[3] - mu) * rs * g4.w + b4.w;
    *(float4*)(out + base + c) = o;
}

// ---------------------------------------------------------------------------
extern "C" void kernel_launch(void* const* d_in, const int* in_sizes, int n_in,
                              void* d_out, int out_size, void* d_ws, size_t ws_size,
                              hipStream_t stream) {
    const float* src = (const float*)d_in[0];
    const float* Wq  = (const float*)d_in[1];
    const float* bq  = (const float*)d_in[2];
    const float* Wk  = (const float*)d_in[3];
    const float* bk  = (const float*)d_in[4];
    const float* Wv  = (const float*)d_in[5];
    const float* bv  = (const float*)d_in[6];
    const float* Wo  = (const float*)d_in[7];
    const float* g1  = (const float*)d_in[8];
    const float* be1 = (const float*)d_in[9];
    const float* W1  = (const float*)d_in[10];
    const float* b1  = (const float*)d_in[11];
    const float* W2  = (const float*)d_in[12];
    const float* b2  = (const float*)d_in[13];
    const float* g2  = (const float*)d_in[14];
    const float* be2 = (const float*)d_in[15];
    char* ws = (char*)d_ws;
    float* out = (float*)d_out;

    // liveness-packed workspace (bytes), ~81 MB:
    u16*   qhp  = (u16*)  (ws + 0);          //  4 MB [bh][s][16]  dead after attn
    u16*   khp  = (u16*)  (ws + 4194304);    //  4 MB              dead after attn
    u16*   vhb  = (u16*)  (ws + 8388608);    //  4 MB              dead after transpose
    u16*   vaug = (u16*)  (ws + 12582912);   //  8 MB [bh][32][2048] dead after attn
    float* part = (float*)(ws + 20971520);   // 21 MB [2][131072][20] dead after combine
    u16*   ctxb = (u16*)  (ws + 41943040);   //  4 MB              dead after Wo
    u16*   yb   = (u16*)  (ws + 46137344);   //  8 MB              dead after LN1
    u16*   hb   = (u16*)  (ws + 0);          // 32 MB reuses dead 0..32M
    u16*   xb   = (u16*)  (ws + 54525952);   //  8 MB  live LN1 -> LN2
    u16*   fb   = (u16*)  (ws + 62914560);   //  8 MB  FFN2 -> LN2
    u16*   srcb = (u16*)  (ws + 71303168);   //  8 MB
    u16*   WqT  = (u16*)  (ws + 79691776);
    u16*   WkT  = (u16*)  (ws + 79757312);
    u16*   WvT  = (u16*)  (ws + 79822848);
    u16*   WoT  = (u16*)  (ws + 79888384);
    u16*   W1T  = (u16*)  (ws + 79953920);   // 512 KB
    u16*   W2T  = (u16*)  (ws + 80478208);   // 512 KB

    // 0) conversions (merged)
    prep_kernel<<<6656, 256, 0, stream>>>(src, srcb, Wq, Wk, Wv, Wo, W1, W2,
                                          WqT, WkT, WvT, WoT, W1T, W2T);
    // 1) QKV -> tight bf16 head layout [bh][s][16]
    qkv_mfma<<<dim3(128, 1, 3), 256, 0, stream>>>(srcb, WqT, WkT, WvT,
                                                  bq, bk, bv, qhp, khp, vhb);
    // 1b) V transpose + ones augmentation
    transpose_v<<<dim3(16, 64), 256, 0, stream>>>(vhb, vaug);
    // 2) split-K flash attention -> fp32 partials
    attn_mfma<<<dim3(32, 64, 2), 128, 0, stream>>>(qhp, khp, vaug, part);
    // 2b) combine partials -> ctx bf16 (S*B, 128)
    attn_combine<<<1024, 256, 0, stream>>>(part, ctxb);
    // 3) yb = ctx @ Wo (bf16 out), BN=64 -> 512 blocks
    mfma_gemm<64, false, false, true><<<dim3(128, 4), 256, 0, stream>>>(
        ctxb, WoT, nullptr, yb, MROWS, DMODEL, DPROJ);
    // 4) xb = bf16(LN1(src + yb))
    ln1_kernel<<<MROWS / 4, 256, 0, stream>>>(src, yb, g1, be1, xb);
    // 5) hb = relu(xb @ W1 + b1) (bf16)
    mfma_gemm<128, true, true, true><<<dim3(128, 8), 256, 0, stream>>>(
        xb, W1T, b1, hb, MROWS, DFF, DMODEL);
    // 6) fb = hb @ W2 + b2 (bf16), BN=64 -> 512 blocks
    mfma_gemm<64, false, true, true><<<dim3(128, 4), 256, 0, stream>>>(
        hb, W2T, b2, fb, MROWS, DMODEL, DFF);
    // 7) out = LN2(xb + fb) fp32
    ln2_kernel<<<MROWS / 4, 256, 0, stream>>>(xb, fb, g2, be2, out);
}

// Round 9
// 240.622 us; speedup vs baseline: 1.2427x; 1.2427x over previous
//
#include <hip/hip_runtime.h>
#include <math.h>

#define SLEN 2048
#define BATCH 8
#define DMODEL 256
#define HEADS 8
#define DPROJ 128
#define DFF 1024
#define DH 16
#define MROWS (SLEN*BATCH)   // 16384

typedef unsigned short u16;
typedef unsigned int u32;
typedef __attribute__((ext_vector_type(8))) short short8;
typedef __attribute__((ext_vector_type(4))) float f32x4;
typedef __attribute__((ext_vector_type(16))) float f32x16;
typedef __attribute__((ext_vector_type(4))) unsigned short u16x4;

__device__ __forceinline__ u16 f2bf(float x) {
    union { float f; u32 u; } v; v.f = x;
    u32 r = v.u + 0x7FFFu + ((v.u >> 16) & 1u);
    return (u16)(r >> 16);
}
__device__ __forceinline__ float bf2f(u16 h) {
    union { u32 u; float f; } v; v.u = ((u32)h) << 16;
    return v.f;
}
__device__ __forceinline__ float fexp2(float x) { return __builtin_amdgcn_exp2f(x); }
// pack bf16(lo),bf16(hi) (truncating) into one dword via v_perm_b32; the
// truncation bias cancels in O/L since L is computed from the same truncated P
__device__ __forceinline__ u32 pack_bf(float lo, float hi) {
    union { float f; u32 u; } a, b; a.f = lo; b.f = hi;
    return __builtin_amdgcn_perm(b.u, a.u, 0x07060302u);
}
// async global->LDS 16B: per-lane global addr, wave-uniform LDS base
__device__ __forceinline__ void gld16(const u16* g, u16* l) {
    __builtin_amdgcn_global_load_lds(
        (const __attribute__((address_space(1))) void*)g,
        (__attribute__((address_space(3))) void*)l, 16, 0, 0);
}

// ---------------------------------------------------------------------------
// prep: src fp32->bf16 (blocks 0..4095) + weight transpose+convert +
// vaug ones-row (row 16 of each bh) fill.
// ---------------------------------------------------------------------------
__global__ void prep_kernel(const float* __restrict__ src, u16* __restrict__ srcb,
                            const float* __restrict__ Wq, const float* __restrict__ Wk,
                            const float* __restrict__ Wv, const float* __restrict__ Wo,
                            const float* __restrict__ W1, const float* __restrict__ W2,
                            u16* __restrict__ WqT, u16* __restrict__ WkT,
                            u16* __restrict__ WvT, u16* __restrict__ WoT,
                            u16* __restrict__ W1T, u16* __restrict__ W2T,
                            u16* __restrict__ va) {
    if (blockIdx.x < 4096) {
        int idx = (blockIdx.x * 256 + threadIdx.x) * 4;
        float4 v = *(const float4*)(src + idx);
        u16x4 o;
        o.x = f2bf(v.x); o.y = f2bf(v.y); o.z = f2bf(v.z); o.w = f2bf(v.w);
        *(u16x4*)(srcb + idx) = o;
        return;
    }
    int i = (blockIdx.x - 4096) * 256 + threadIdx.x;
    if (i < 32768) {                       // WqT [128][256]
        int n = i >> 8, k = i & 255;
        WqT[i] = f2bf(Wq[k * 128 + n]);
    } else if (i < 65536) {
        int j = i - 32768; int n = j >> 8, k = j & 255;
        WkT[j] = f2bf(Wk[k * 128 + n]);
    } else if (i < 98304) {
        int j = i - 65536; int n = j >> 8, k = j & 255;
        WvT[j] = f2bf(Wv[k * 128 + n]);
    } else if (i < 131072) {               // WoT [256][128]
        int j = i - 98304; int n = j >> 7, k = j & 127;
        WoT[j] = f2bf(Wo[k * 256 + n]);
    } else if (i < 393216) {               // W1T [1024][256]
        int j = i - 131072; int n = j >> 8, k = j & 255;
        W1T[j] = f2bf(W1[k * 1024 + n]);
    } else if (i < 655360) {               // W2T [256][1024]
        int j = i - 393216; int n = j >> 10, k = j & 1023;
        W2T[j] = f2bf(W2[k * 256 + n]);
    } else if (i < 786432) {               // vaug ones row: [bh][16][2048]
        int j = i - 655360; int bh = j >> 11, col = j & 2047;
        va[(size_t)bh * 65536 + 16 * 2048 + col] = (u16)0x3F80;
    }
}

// ---------------------------------------------------------------------------
// bf16 MFMA GEMM with async global->LDS staging + XOR chunk swizzle.
// ---------------------------------------------------------------------------
template<int BN, bool RELU, bool HAS_BIAS, bool OUT_BF16>
__global__ void mfma_gemm(const u16* __restrict__ A, const u16* __restrict__ BT,
                          const float* __restrict__ bias, void* __restrict__ Cout,
                          int M, int N, int K) {
    constexpr int NJ = BN / 32;
    __shared__ __align__(16) u16 As[128 * 32];
    __shared__ __align__(16) u16 Bs[BN * 32];
    const int tid = threadIdx.x;
    const int row0 = blockIdx.x * 128;
    const int col0 = blockIdx.y * BN;
    const int w = tid >> 6, l = tid & 63;
    const int wr = (w & 1) * 64, wc = (w >> 1) * (BN / 2);
    const int lcol = l & 15, lrow = (l >> 4) * 4, g = l >> 4;
    const int sl = l >> 2;
    const int swc = ((l & 3) ^ (sl & 3)) * 8;
    const int fsw = (g ^ (lcol & 3)) * 8;

    const u16* Ag0 = A + (size_t)(row0 + 16 * w + sl) * K + swc;
    const u16* Ag1 = Ag0 + (size_t)64 * K;
    const u16* Bg0 = BT + (size_t)(col0 + 16 * w + sl) * K + swc;
    const u16* Bg1 = Bg0 + (size_t)64 * K;
    u16* lA0 = As + (16 * w) * 32;
    u16* lA1 = As + (16 * w + 64) * 32;
    u16* lB0 = Bs + (16 * w) * 32;
    u16* lB1 = Bs + (16 * w + 64) * 32;

    f32x4 acc[4][NJ] = {};
    for (int k0 = 0; k0 < K; k0 += 32) {
        gld16(Ag0 + k0, lA0);
        gld16(Ag1 + k0, lA1);
        gld16(Bg0 + k0, lB0);
        if (BN == 128) gld16(Bg1 + k0, lB1);
        __syncthreads();
        short8 af[4], bf[NJ];
        #pragma unroll
        for (int i = 0; i < 4; ++i)
            af[i] = *(const short8*)(As + (wr + i * 16 + lcol) * 32 + fsw);
        #pragma unroll
        for (int j = 0; j < NJ; ++j)
            bf[j] = *(const short8*)(Bs + (wc + j * 16 + lcol) * 32 + fsw);
        #pragma unroll
        for (int i = 0; i < 4; ++i)
            #pragma unroll
            for (int j = 0; j < NJ; ++j)
                acc[i][j] = __builtin_amdgcn_mfma_f32_16x16x32_bf16(
                    af[i], bf[j], acc[i][j], 0, 0, 0);
        __syncthreads();
    }
    float bv[NJ];
    #pragma unroll
    for (int j = 0; j < NJ; ++j)
        bv[j] = HAS_BIAS ? bias[col0 + wc + j * 16 + lcol] : 0.f;
    #pragma unroll
    for (int i = 0; i < 4; ++i) {
        #pragma unroll
        for (int r = 0; r < 4; ++r) {
            size_t grow = row0 + wr + i * 16 + lrow + r;
            #pragma unroll
            for (int j = 0; j < NJ; ++j) {
                int gcol = col0 + wc + j * 16 + lcol;
                float c = acc[i][j][r] + bv[j];
                if (RELU) c = fmaxf(c, 0.f);
                if (OUT_BF16) ((u16*)Cout)[grow * N + gcol] = f2bf(c);
                else          ((float*)Cout)[grow * N + gcol] = c;
            }
        }
    }
}

// ---------------------------------------------------------------------------
// QKV MFMA GEMM -> bf16 head layouts:
//   q -> qhp [bh][s][16], pre-scaled by 0.25*log2e
//   k -> khp [bh][s][16]
//   v -> vaug [bh][32][2048] rows 0..15 = V^T (transposed write, fused)
// ---------------------------------------------------------------------------
__global__ void qkv_mfma(const u16* __restrict__ A,
                         const u16* __restrict__ WqT, const u16* __restrict__ WkT,
                         const u16* __restrict__ WvT,
                         const float* __restrict__ bq, const float* __restrict__ bk,
                         const float* __restrict__ bv,
                         u16* __restrict__ qhp, u16* __restrict__ khp,
                         u16* __restrict__ va) {
    const int which = blockIdx.z;
    const u16* BT   = which == 0 ? WqT : (which == 1 ? WkT : WvT);
    const float* bs = which == 0 ? bq : (which == 1 ? bk : bv);
    const float scale = which == 0 ? 0.25f * 1.44269504f : 1.0f;
    __shared__ __align__(16) u16 As[128 * 32];
    __shared__ __align__(16) u16 Bs[128 * 32];
    const int tid = threadIdx.x;
    const int row0 = blockIdx.x * 128;
    const int w = tid >> 6, l = tid & 63;
    const int wr = (w & 1) * 64, wc = (w >> 1) * 64;
    const int lcol = l & 15, lrow = (l >> 4) * 4, g = l >> 4;
    const int sl = l >> 2;
    const int swc = ((l & 3) ^ (sl & 3)) * 8;
    const int fsw = (g ^ (lcol & 3)) * 8;

    const u16* Ag0 = A + (size_t)(row0 + 16 * w + sl) * DMODEL + swc;
    const u16* Ag1 = Ag0 + (size_t)64 * DMODEL;
    const u16* Bg0 = BT + (size_t)(16 * w + sl) * DMODEL + swc;
    const u16* Bg1 = Bg0 + (size_t)64 * DMODEL;
    u16* lA0 = As + (16 * w) * 32;
    u16* lA1 = As + (16 * w + 64) * 32;
    u16* lB0 = Bs + (16 * w) * 32;
    u16* lB1 = Bs + (16 * w + 64) * 32;

    f32x4 acc[4][4] = {};
    for (int k0 = 0; k0 < DMODEL; k0 += 32) {
        gld16(Ag0 + k0, lA0);
        gld16(Ag1 + k0, lA1);
        gld16(Bg0 + k0, lB0);
        gld16(Bg1 + k0, lB1);
        __syncthreads();
        short8 af[4], bf[4];
        #pragma unroll
        for (int i = 0; i < 4; ++i)
            af[i] = *(const short8*)(As + (wr + i * 16 + lcol) * 32 + fsw);
        #pragma unroll
        for (int j = 0; j < 4; ++j)
            bf[j] = *(const short8*)(Bs + (wc + j * 16 + lcol) * 32 + fsw);
        #pragma unroll
        for (int i = 0; i < 4; ++i)
            #pragma unroll
            for (int j = 0; j < 4; ++j)
                acc[i][j] = __builtin_amdgcn_mfma_f32_16x16x32_bf16(
                    af[i], bf[j], acc[i][j], 0, 0, 0);
        __syncthreads();
    }
    #pragma unroll
    for (int i = 0; i < 4; ++i) {
        #pragma unroll
        for (int r = 0; r < 4; ++r) {
            int grow = row0 + wr + i * 16 + lrow + r;
            int b = grow & 7, s = grow >> 3;
            #pragma unroll
            for (int j = 0; j < 4; ++j) {
                int gcol = wc + j * 16 + lcol;
                int h = gcol >> 4, d = gcol & 15;
                float c = acc[i][j][r] + bs[gcol];
                if (which == 2) {
                    // fused transpose: vaug[bh][d][s]
                    va[((size_t)(b * 8 + h) * 32 + d) * SLEN + s] = f2bf(c);
                } else {
                    u16* outp = which == 0 ? qhp : khp;
                    outp[((size_t)(b * 8 + h) * SLEN + s) * 16 + d] = f2bf(c * scale);
                }
            }
        }
    }
}

// ---------------------------------------------------------------------------
// MFMA flash attention v7 — full-K, 2-wave blocks (2048 blocks, 16 waves/CU),
// 32x32x16 (K=dh=16 exact), no-max softmax, K+V fragments prefetched one tile
// ahead, per-wave P at stride 68 u16 (b64 ops, zero conflicts — verified r8),
// L free in accumulator col 16 via ones-augmented V. Epilogue: per-wave LDS
// O-buffer -> coalesced bf16 ctx write. No split-K, no partials.
// ---------------------------------------------------------------------------
__global__ __launch_bounds__(128, 4)
void attn_mfma(const u16* __restrict__ qg, const u16* __restrict__ kg,
               const u16* __restrict__ va, u16* __restrict__ ctx) {
    __shared__ __align__(16) u16 Ps[2 * 32 * 68];   // 8704 B
    const int bh = blockIdx.y;
    const int tid = threadIdx.x;
    const int w = tid >> 6, l = tid & 63;
    const int n = l & 31, h5 = l >> 5;
    u16* Pw = Ps + w * (32 * 68);

    const int qbase = blockIdx.x * 64 + w * 32;
    const short8 qf = *(const short8*)(
        qg + ((size_t)bh * SLEN + qbase + n) * 16 + h5 * 8);
    const u16* kb = kg + (size_t)bh * SLEN * 16;
    const u16* vb = va + ((size_t)bh * 32 + n) * SLEN + h5 * 8;

    f32x16 oacc = {};
    short8 kf0 = *(const short8*)(kb + (size_t)n * 16 + h5 * 8);
    short8 kf1 = *(const short8*)(kb + (size_t)(32 + n) * 16 + h5 * 8);
    short8 vf[4];
    #pragma unroll
    for (int st = 0; st < 4; ++st)
        vf[st] = *(const short8*)(vb + st * 16);

    for (int kt = 0; kt < 32; ++kt) {
        const int k0 = kt * 64;
        // S^T = K·Q^T (D[m=key][n=qrow])
        f32x16 z = {};
        f32x16 s0 = __builtin_amdgcn_mfma_f32_32x32x16_bf16(kf0, qf, z, 0, 0, 0);
        f32x16 s1 = __builtin_amdgcn_mfma_f32_32x32x16_bf16(kf1, qf, z, 0, 0, 0);
        // prefetch next tile's K and V fragments (hides L2 latency)
        const int kn = (k0 + 64) & (SLEN - 1);
        short8 kf0n = *(const short8*)(kb + (size_t)(kn + n) * 16 + h5 * 8);
        short8 kf1n = *(const short8*)(kb + (size_t)(kn + 32 + n) * 16 + h5 * 8);
        short8 vfn[4];
        #pragma unroll
        for (int st = 0; st < 4; ++st)
            vfn[st] = *(const short8*)(vb + kn + st * 16);
        // P = exp2(S): reg quad r4 covers keys 8r4 + 4h5 + {0..3}
        #pragma unroll
        for (int r4 = 0; r4 < 4; ++r4) {
            uint2 d;
            d.x = pack_bf(fexp2(s0[r4 * 4 + 0]), fexp2(s0[r4 * 4 + 1]));
            d.y = pack_bf(fexp2(s0[r4 * 4 + 2]), fexp2(s0[r4 * 4 + 3]));
            *(uint2*)(Pw + n * 68 + 8 * r4 + 4 * h5) = d;
        }
        #pragma unroll
        for (int r4 = 0; r4 < 4; ++r4) {
            uint2 d;
            d.x = pack_bf(fexp2(s1[r4 * 4 + 0]), fexp2(s1[r4 * 4 + 1]));
            d.y = pack_bf(fexp2(s1[r4 * 4 + 2]), fexp2(s1[r4 * 4 + 3]));
            *(uint2*)(Pw + n * 68 + 32 + 8 * r4 + 4 * h5) = d;
        }
        // O(+L) += P @ Vaug : A[m=q][k=key], B[k=key][n=dh|L]
        #pragma unroll
        for (int st = 0; st < 4; ++st) {
            const u16* rp = Pw + n * 68 + st * 16 + h5 * 8;
            union { uint2 q2[2]; short8 v; } ap;
            ap.q2[0] = *(const uint2*)rp;
            ap.q2[1] = *(const uint2*)(rp + 4);
            oacc = __builtin_amdgcn_mfma_f32_32x32x16_bf16(ap.v, vf[st], oacc, 0, 0, 0);
        }
        kf0 = kf0n; kf1 = kf1n;
        #pragma unroll
        for (int st = 0; st < 4; ++st) vf[st] = vfn[st];
    }
    // epilogue: oacc cols 0..16 -> per-wave LDS Ob[32 q][20 f32], then
    // normalized coalesced bf16 ctx write (row-major (S*B,128)).
    float* Ob = (float*)Pw;
    if (n <= 16) {
        #pragma unroll
        for (int r = 0; r < 16; ++r) {
            int qq = (r & 3) + 8 * (r >> 2) + 4 * h5;
            Ob[qq * 20 + n] = oacc[r];
        }
    }
    __syncthreads();
    const int q = l >> 1, half = l & 1;
    f32x4 o0 = *(const f32x4*)(Ob + q * 20 + half * 8);
    f32x4 o1 = *(const f32x4*)(Ob + q * 20 + half * 8 + 4);
    float rcp = 1.0f / Ob[q * 20 + 16];
    u16x4 p0, p1;
    p0.x = f2bf(o0[0] * rcp); p0.y = f2bf(o0[1] * rcp);
    p0.z = f2bf(o0[2] * rcp); p0.w = f2bf(o0[3] * rcp);
    p1.x = f2bf(o1[0] * rcp); p1.y = f2bf(o1[1] * rcp);
    p1.z = f2bf(o1[2] * rcp); p1.w = f2bf(o1[3] * rcp);
    const int b = bh >> 3, h = bh & 7;
    const int qrow = qbase + q;
    u16* dst = ctx + ((size_t)qrow * BATCH + b) * DPROJ + h * DH + half * 8;
    *(u16x4*)dst = p0;
    *(u16x4*)(dst + 4) = p1;
}

// ---------------------------------------------------------------------------
// LN, wave-per-row (64 lanes x 4 elems), no barriers.
// ln1: xb = bf16(LN(srcb_bf16 + yb_bf16))  (bf16 residual: err << threshold)
// ---------------------------------------------------------------------------
__global__ void ln1_kernel(const u16* __restrict__ srcb, const u16* __restrict__ y,
                           const float* __restrict__ g, const float* __restrict__ bb,
                           u16* __restrict__ xb) {
    const int w = threadIdx.x >> 6, l = threadIdx.x & 63;
    const int row = blockIdx.x * 4 + w;
    const int c = l * 4;
    size_t base = (size_t)row * DMODEL;
    u16x4 s4 = *(const u16x4*)(srcb + base + c);
    u16x4 y4 = *(const u16x4*)(y + base + c);
    float v[4] = { bf2f(s4.x) + bf2f(y4.x), bf2f(s4.y) + bf2f(y4.y),
                   bf2f(s4.z) + bf2f(y4.z), bf2f(s4.w) + bf2f(y4.w) };
    float sum = v[0] + v[1] + v[2] + v[3];
    float ss  = v[0]*v[0] + v[1]*v[1] + v[2]*v[2] + v[3]*v[3];
    #pragma unroll
    for (int off = 1; off < 64; off <<= 1) {
        sum += __shfl_xor(sum, off);
        ss  += __shfl_xor(ss, off);
    }
    float mu = sum * (1.0f / 256.0f);
    float var = ss * (1.0f / 256.0f) - mu * mu;
    float rs = rsqrtf(var + 1e-5f);
    float4 g4 = *(const float4*)(g + c);
    float4 b4 = *(const float4*)(bb + c);
    u16x4 o;
    o.x = f2bf((v[0] - mu) * rs * g4.x + b4.x);
    o.y = f2bf((v[1] - mu) * rs * g4.y + b4.y);
    o.z = f2bf((v[2] - mu) * rs * g4.z + b4.z);
    o.w = f2bf((v[3] - mu) * rs * g4.w + b4.w);
    *(u16x4*)(xb + base + c) = o;
}

__global__ void ln2_kernel(const u16* __restrict__ x, const u16* __restrict__ f,
                           const float* __restrict__ g, const float* __restrict__ bb,
                           float* __restrict__ out) {
    const int w = threadIdx.x >> 6, l = threadIdx.x & 63;
    const int row = blockIdx.x * 4 + w;
    const int c = l * 4;
    size_t base = (size_t)row * DMODEL;
    u16x4 x4 = *(const u16x4*)(x + base + c);
    u16x4 f4 = *(const u16x4*)(f + base + c);
    float v[4] = { bf2f(x4.x) + bf2f(f4.x), bf2f(x4.y) + bf2f(f4.y),
                   bf2f(x4.z) + bf2f(f4.z), bf2f(x4.w) + bf2f(f4.w) };
    float sum = v[0] + v[1] + v[2] + v[3];
    float ss  = v[0]*v[0] + v[1]*v[1] + v[2]*v[2] + v[3]*v[3];
    #pragma unroll
    for (int off = 1; off < 64; off <<= 1) {
        sum += __shfl_xor(sum, off);
        ss  += __shfl_xor(ss, off);
    }
    float mu = sum * (1.0f / 256.0f);
    float var = ss * (1.0f / 256.0f) - mu * mu;
    float rs = rsqrtf(var + 1e-5f);
    float4 g4 = *(const float4*)(g + c);
    float4 b4 = *(const float4*)(bb + c);
    float4 o;
    o.x = (v[0] - mu) * rs * g4.x + b4.x;
    o.y = (v[1] - mu) * rs * g4.y + b4.y;
    o.z = (v[2] - mu) * rs * g4.z + b4.z;
    o.w = (v[3] - mu) * rs * g4.w + b4.w;
    *(float4*)(out + base + c) = o;
}

// ---------------------------------------------------------------------------
extern "C" void kernel_launch(void* const* d_in, const int* in_sizes, int n_in,
                              void* d_out, int out_size, void* d_ws, size_t ws_size,
                              hipStream_t stream) {
    const float* src = (const float*)d_in[0];
    const float* Wq  = (const float*)d_in[1];
    const float* bq  = (const float*)d_in[2];
    const float* Wk  = (const float*)d_in[3];
    const float* bk  = (const float*)d_in[4];
    const float* Wv  = (const float*)d_in[5];
    const float* bv  = (const float*)d_in[6];
    const float* Wo  = (const float*)d_in[7];
    const float* g1  = (const float*)d_in[8];
    const float* be1 = (const float*)d_in[9];
    const float* W1  = (const float*)d_in[10];
    const float* b1  = (const float*)d_in[11];
    const float* W2  = (const float*)d_in[12];
    const float* b2  = (const float*)d_in[13];
    const float* g2  = (const float*)d_in[14];
    const float* be2 = (const float*)d_in[15];
    char* ws = (char*)d_ws;
    float* out = (float*)d_out;

    // liveness-packed workspace (bytes), ~60 MB:
    u16* qhp  = (u16*)(ws + 0);          //  4 MB [bh][s][16]    dead after attn
    u16* khp  = (u16*)(ws + 4194304);    //  4 MB                dead after attn
    u16* vaug = (u16*)(ws + 8388608);    //  8 MB [bh][32][2048] dead after attn
    u16* ctxb = (u16*)(ws + 16777216);   //  4 MB                dead after Wo
    u16* yb   = (u16*)(ws + 20971520);   //  8 MB                dead after LN1
    u16* hb   = (u16*)(ws + 0);          // 32 MB reuses dead 0..32M
    u16* xb   = (u16*)(ws + 33554432);   //  8 MB  live LN1 -> LN2
    u16* fb   = (u16*)(ws + 41943040);   //  8 MB  FFN2 -> LN2
    u16* srcb = (u16*)(ws + 50331648);   //  8 MB  live to LN1
    u16* WqT  = (u16*)(ws + 58720256);
    u16* WkT  = (u16*)(ws + 58785792);
    u16* WvT  = (u16*)(ws + 58851328);
    u16* WoT  = (u16*)(ws + 58916864);
    u16* W1T  = (u16*)(ws + 58982400);   // 512 KB
    u16* W2T  = (u16*)(ws + 59506688);   // 512 KB

    // 0) conversions + vaug ones row (merged)
    prep_kernel<<<7168, 256, 0, stream>>>(src, srcb, Wq, Wk, Wv, Wo, W1, W2,
                                          WqT, WkT, WvT, WoT, W1T, W2T, vaug);
    // 1) QKV -> tight head layouts; V written transposed into vaug (fused)
    qkv_mfma<<<dim3(128, 1, 3), 256, 0, stream>>>(srcb, WqT, WkT, WvT,
                                                  bq, bk, bv, qhp, khp, vaug);
    // 2) full-K flash attention -> ctx bf16 (S*B, 128)
    attn_mfma<<<dim3(32, 64), 128, 0, stream>>>(qhp, khp, vaug, ctxb);
    // 3) yb = ctx @ Wo (bf16 out), BN=64 -> 512 blocks
    mfma_gemm<64, false, false, true><<<dim3(128, 4), 256, 0, stream>>>(
        ctxb, WoT, nullptr, yb, MROWS, DMODEL, DPROJ);
    // 4) xb = bf16(LN1(srcb + yb))
    ln1_kernel<<<MROWS / 4, 256, 0, stream>>>(srcb, yb, g1, be1, xb);
    // 5) hb = relu(xb @ W1 + b1) (bf16)
    mfma_gemm<128, true, true, true><<<dim3(128, 8), 256, 0, stream>>>(
        xb, W1T, b1, hb, MROWS, DFF, DMODEL);
    // 6) fb = hb @ W2 + b2 (bf16), BN=64 -> 512 blocks
    mfma_gemm<64, false, true, true><<<dim3(128, 4), 256, 0, stream>>>(
        hb, W2T, b2, fb, MROWS, DMODEL, DFF);
    // 7) out = LN2(xb + fb) fp32
    ln2_kernel<<<MROWS / 4, 256, 0, stream>>>(xb, fb, g2, be2, out);
}